// Round 7
// baseline (379.898 us; speedup 1.0000x reference)
//
#include <hip/hip_runtime.h>
#include <hip/hip_bf16.h>
#include <math.h>

constexpr int B_ = 8, L_ = 256, D_ = 256, H_ = 8, DK_ = 32, NL_ = 4, V_ = 2048, FF_ = 1024;
constexpr int N_ = B_ * L_;
constexpr float EPS_ = 1e-5f;

typedef short bf16x8 __attribute__((ext_vector_type(8)));
typedef float f32x4 __attribute__((ext_vector_type(4)));
typedef _Float16 f16x4 __attribute__((ext_vector_type(4)));

__device__ __forceinline__ short f2b(float f) {
    union { __hip_bfloat16 h; short s; } u;
    u.h = __float2bfloat16(f);
    return u.s;
}

// x[n,d] = value_tab[tok]*sqrt(D) + coord_tab[p%3] + pos_tab[p/3]  (fp32 residual stream)
__global__ void embed_kernel(const int* __restrict__ tokens, const int* __restrict__ positions,
                             const float* __restrict__ vtab, const float* __restrict__ ctab,
                             const float* __restrict__ ptab, float* __restrict__ x) {
    int n = blockIdx.x, d = threadIdx.x;
    int tok = tokens[n], p = positions[n];
    x[n * D_ + d] = vtab[tok * D_ + d] * 16.0f + ctab[(p % 3) * D_ + d] + ptab[(p / 3) * D_ + d];
}

// fp32 [K,N] -> bf16 [N,K] tiled transpose; batch via blockIdx.z
__global__ void transpose_w(const float* __restrict__ src, short* __restrict__ dst, int K, int Nn) {
    __shared__ float tile[32][33];
    int n0 = blockIdx.x * 32, k0 = blockIdx.y * 32;
    size_t base = (size_t)blockIdx.z * K * Nn;
    src += base;
    dst += base;
    int tx = threadIdx.x, ty = threadIdx.y;  // 32 x 8
#pragma unroll
    for (int i = 0; i < 32; i += 8)
        tile[ty + i][tx] = src[(size_t)(k0 + ty + i) * Nn + n0 + tx];
    __syncthreads();
#pragma unroll
    for (int i = 0; i < 32; i += 8)
        dst[(size_t)(n0 + ty + i) * K + k0 + tx] = f2b(tile[tx][ty + i]);
}

// all four DxD weight families in one launch: z = layer*4 + matrix
__global__ void transpose_w4(const float* __restrict__ Wq, const float* __restrict__ Wk,
                             const float* __restrict__ Wv, const float* __restrict__ Wo,
                             short* __restrict__ wqT, short* __restrict__ wkT,
                             short* __restrict__ wvT, short* __restrict__ woT) {
    __shared__ float tile[32][33];
    int z = blockIdx.z, m = z & 3, layer = z >> 2;
    const float* src = (m == 0) ? Wq : (m == 1) ? Wk : (m == 2) ? Wv : Wo;
    short* dst = (m == 0) ? wqT : (m == 1) ? wkT : (m == 2) ? wvT : woT;
    src += (size_t)layer * D_ * D_;
    dst += (size_t)layer * D_ * D_;
    int n0 = blockIdx.x * 32, k0 = blockIdx.y * 32;
    int tx = threadIdx.x, ty = threadIdx.y;
#pragma unroll
    for (int i = 0; i < 32; i += 8)
        tile[ty + i][tx] = src[(size_t)(k0 + ty + i) * D_ + n0 + tx];
    __syncthreads();
#pragma unroll
    for (int i = 0; i < 32; i += 8)
        dst[(size_t)(n0 + ty + i) * D_ + k0 + tx] = f2b(tile[tx][ty + i]);
}

// 64x64 tile bf16 MFMA GEMM body (BK=32, register-prefetch staging, stride-40 LDS:
// 80B row stride = 20 banks -> worst 2-way aliasing = free).
// FUSE_LN: A is fp32 [M,K=256], per-row LN (mean/rsqrt computed in stats phase)
// applied during staging with gamma/beta indexed by k.
// EPI: 1 = bias+relu -> bf16; 2 = atomicAdd fp32 (+bias from kz==0); 3 = bias -> fp32;
//      4 = store bf16; 6 = store f16 TRANSPOSED (Ct[col][row], stride M)
template <int EPI, bool HAS_BIAS, bool FUSE_LN>
__device__ __forceinline__ void gemm_body(short (*As)[40], short (*Bs)[40], float (*stats)[2],
                                          const float* __restrict__ Af, const short* __restrict__ A,
                                          const short* __restrict__ Bt,
                                          const float* __restrict__ lng, const float* __restrict__ lnb,
                                          const float* __restrict__ bias, float* __restrict__ Cf,
                                          short* __restrict__ Cb, int M, int K, int Nout,
                                          int kbeg, int kend, int kz) {
    int t = threadIdx.x;
    int m0 = blockIdx.x * 64, n0 = blockIdx.y * 64;
    int lane = t & 63, w = t >> 6;
    int mo = (w & 1) * 32, no = (w >> 1) * 32;
    int quad = lane >> 4, r = lane & 15;

    if (FUSE_LN) {
        // per-row LN stats: wave w handles rows m0+16w .. +15; lanes cover K=256 as float4
#pragma unroll 4
        for (int rr = 0; rr < 16; ++rr) {
            int row = m0 + w * 16 + rr;
            float4 xv = *(const float4*)&Af[(size_t)row * K + lane * 4];
            float s1 = (xv.x + xv.y) + (xv.z + xv.w);
            float s2 = (xv.x * xv.x + xv.y * xv.y) + (xv.z * xv.z + xv.w * xv.w);
#pragma unroll
            for (int off = 1; off < 64; off <<= 1) {
                s1 += __shfl_xor(s1, off, 64);
                s2 += __shfl_xor(s2, off, 64);
            }
            if (lane == 0) {
                float mean = s1 * (1.0f / 256.0f);
                float var = s2 * (1.0f / 256.0f) - mean * mean;
                stats[w * 16 + rr][0] = mean;
                stats[w * 16 + rr][1] = rsqrtf(var + EPS_);
            }
        }
        __syncthreads();
    }

    f32x4 acc00 = {}, acc01 = {}, acc10 = {}, acc11 = {};
    int sr = t >> 2, sc = (t & 3) * 8;  // staging: row sr, shorts sc..sc+7
    const short* Bg = &Bt[(size_t)(n0 + sr) * K + sc];
    int4 bR = *(const int4*)(Bg + kbeg);
    int4 aR;
    float4 a0R, a1R, g0R, g1R, b0R, b1R;
    if (FUSE_LN) {
        const float* Ap = &Af[(size_t)(m0 + sr) * K + sc];
        a0R = *(const float4*)(Ap + kbeg);
        a1R = *(const float4*)(Ap + kbeg + 4);
        g0R = *(const float4*)(lng + kbeg + sc);
        g1R = *(const float4*)(lng + kbeg + sc + 4);
        b0R = *(const float4*)(lnb + kbeg + sc);
        b1R = *(const float4*)(lnb + kbeg + sc + 4);
    } else {
        aR = *(const int4*)(&A[(size_t)(m0 + sr) * K + sc] + kbeg);
    }
    for (int k0 = kbeg; k0 < kend; k0 += 32) {
        __syncthreads();
        if (FUSE_LN) {
            float m_ = stats[sr][0], rs_ = stats[sr][1];
            float av[8] = {a0R.x, a0R.y, a0R.z, a0R.w, a1R.x, a1R.y, a1R.z, a1R.w};
            float gv[8] = {g0R.x, g0R.y, g0R.z, g0R.w, g1R.x, g1R.y, g1R.z, g1R.w};
            float bv[8] = {b0R.x, b0R.y, b0R.z, b0R.w, b1R.x, b1R.y, b1R.z, b1R.w};
            union { short s[8]; int4 v; } y;
#pragma unroll
            for (int p = 0; p < 8; ++p) y.s[p] = f2b((av[p] - m_) * rs_ * gv[p] + bv[p]);
            *(int4*)&As[sr][sc] = y.v;
        } else {
            *(int4*)&As[sr][sc] = aR;
        }
        *(int4*)&Bs[sr][sc] = bR;
        __syncthreads();
        if (k0 + 32 < kend) {
            int kn = k0 + 32;
            bR = *(const int4*)(Bg + kn);
            if (FUSE_LN) {
                const float* Ap = &Af[(size_t)(m0 + sr) * K + sc];
                a0R = *(const float4*)(Ap + kn);
                a1R = *(const float4*)(Ap + kn + 4);
                g0R = *(const float4*)(lng + kn + sc);
                g1R = *(const float4*)(lng + kn + sc + 4);
                b0R = *(const float4*)(lnb + kn + sc);
                b1R = *(const float4*)(lnb + kn + sc + 4);
            } else {
                aR = *(const int4*)(&A[(size_t)(m0 + sr) * K + sc] + kn);
            }
        }
        bf16x8 a0 = *(const bf16x8*)&As[mo + r][quad * 8];
        bf16x8 a1 = *(const bf16x8*)&As[mo + 16 + r][quad * 8];
        bf16x8 b0 = *(const bf16x8*)&Bs[no + r][quad * 8];
        bf16x8 b1 = *(const bf16x8*)&Bs[no + 16 + r][quad * 8];
        acc00 = __builtin_amdgcn_mfma_f32_16x16x32_bf16(a0, b0, acc00, 0, 0, 0);
        acc01 = __builtin_amdgcn_mfma_f32_16x16x32_bf16(a0, b1, acc01, 0, 0, 0);
        acc10 = __builtin_amdgcn_mfma_f32_16x16x32_bf16(a1, b0, acc10, 0, 0, 0);
        acc11 = __builtin_amdgcn_mfma_f32_16x16x32_bf16(a1, b1, acc11, 0, 0, 0);
    }
#pragma unroll
    for (int i = 0; i < 2; ++i) {
#pragma unroll
        for (int j = 0; j < 2; ++j) {
            f32x4 acc = (i == 0) ? (j == 0 ? acc00 : acc01) : (j == 0 ? acc10 : acc11);
            int col = n0 + no + j * 16 + r;
            int rbase = m0 + mo + i * 16 + quad * 4;
            if (EPI == 6) {
                f16x4 t4;
#pragma unroll
                for (int p = 0; p < 4; ++p) t4[p] = (_Float16)acc[p];
                *(f16x4*)&((_Float16*)Cb)[(size_t)col * M + rbase] = t4;
            } else {
                float bval = HAS_BIAS ? bias[col] : 0.f;
#pragma unroll
                for (int p = 0; p < 4; ++p) {
                    int row = rbase + p;
                    float v = acc[p];
                    if (EPI == 1) {
                        Cb[(size_t)row * Nout + col] = f2b(fmaxf(v + bval, 0.f));
                    } else if (EPI == 2) {
                        float add = v + ((HAS_BIAS && kz == 0) ? bval : 0.f);
                        atomicAdd(&Cf[(size_t)row * Nout + col], add);
                    } else if (EPI == 3) {
                        Cf[(size_t)row * Nout + col] = v + bval;
                    } else if (EPI == 4) {
                        Cb[(size_t)row * Nout + col] = f2b(v);
                    }
                }
            }
        }
    }
}

// fused LN1 + Q/K/V projection: q,k -> bf16 [N,D]; v -> f16 TRANSPOSED [D,N]
__global__ __launch_bounds__(256) void gemm_qkv(const float* __restrict__ x, const short* __restrict__ wq,
                                                const short* __restrict__ wk, const short* __restrict__ wv,
                                                const float* __restrict__ lng, const float* __restrict__ lnb,
                                                short* __restrict__ q, short* __restrict__ k,
                                                _Float16* __restrict__ vt, int M, int K, int Nout) {
    __shared__ short As[64][40];
    __shared__ short Bs[64][40];
    __shared__ float stats[64][2];
    if (blockIdx.z == 0)
        gemm_body<4, false, true>(As, Bs, stats, x, nullptr, wq, lng, lnb, nullptr, nullptr, q, M, K, Nout, 0, K, 0);
    else if (blockIdx.z == 1)
        gemm_body<4, false, true>(As, Bs, stats, x, nullptr, wk, lng, lnb, nullptr, nullptr, k, M, K, Nout, 0, K, 0);
    else
        gemm_body<6, false, true>(As, Bs, stats, x, nullptr, wv, lng, lnb, nullptr, nullptr, (short*)vt, M, K, Nout, 0, K, 0);
}

// split-K accumulate into fp32 residual stream (bias applied by the kz==0 split only)
template <int SPLITK, bool HAS_BIAS>
__global__ __launch_bounds__(256) void gemm_accum(const short* __restrict__ A, const short* __restrict__ Bt,
                                                  const float* __restrict__ bias, float* __restrict__ C,
                                                  int M, int K, int Nout) {
    __shared__ short As[64][40];
    __shared__ short Bs[64][40];
    int Kp = K / SPLITK;
    int kz = blockIdx.z;
    gemm_body<2, HAS_BIAS, false>(As, Bs, nullptr, nullptr, A, Bt, nullptr, nullptr, bias, C, nullptr,
                                  M, K, Nout, kz * Kp, kz * Kp + Kp, kz);
}

// fused LN2 + W1 + bias + relu -> bf16
__global__ __launch_bounds__(256) void gemm_lnrelu(const float* __restrict__ x, const short* __restrict__ Bt,
                                                   const float* __restrict__ lng, const float* __restrict__ lnb,
                                                   const float* __restrict__ bias, short* __restrict__ C,
                                                   int M, int K, int Nout) {
    __shared__ short As[64][40];
    __shared__ short Bs[64][40];
    __shared__ float stats[64][2];
    gemm_body<1, true, true>(As, Bs, stats, x, nullptr, Bt, lng, lnb, bias, nullptr, C, M, K, Nout, 0, K, 0);
}

// fused LNf + generator + bias -> fp32
__global__ __launch_bounds__(256) void gemm_lnbias(const float* __restrict__ x, const short* __restrict__ Bt,
                                                   const float* __restrict__ lng, const float* __restrict__ lnb,
                                                   const float* __restrict__ bias, float* __restrict__ C,
                                                   int M, int K, int Nout) {
    __shared__ short As[64][40];
    __shared__ short Bs[64][40];
    __shared__ float stats[64][2];
    gemm_body<3, true, true>(As, Bs, stats, x, nullptr, Bt, lng, lnb, bias, C, nullptr, M, K, Nout, 0, K, 0);
}

// MFMA flash attention. One wave per (b,h,q-tile of 16). V is f16 transposed [D,N]
// -> PV B-fragments are two 8B vector loads per tile.
__global__ __launch_bounds__(64) void attn_kernel(const short* __restrict__ q,
                                                  const short* __restrict__ k,
                                                  const _Float16* __restrict__ vt,
                                                  short* __restrict__ z) {
    int blk = blockIdx.x;
    int bh = blk & 63;
    int qt = 15 - (blk >> 6);  // heavy q-tiles dispatched first
    int b = bh >> 3, h = bh & 7;
    int lane = threadIdx.x;
    int r = lane & 15, quad = lane >> 4;
    int row0 = b * L_;

    bf16x8 qf = *(const bf16x8*)&q[(size_t)(row0 + qt * 16 + r) * D_ + h * DK_ + quad * 8];
    f32x4 O0 = {}, O1 = {};
    float mA = -1e30f, den = 0.f;
    int nk = qt + 1;

    const _Float16* vta = vt + (size_t)(h * DK_ + r) * N_ + row0 + quad * 4;
    const _Float16* vtb = vt + (size_t)(h * DK_ + 16 + r) * N_ + row0 + quad * 4;
    bf16x8 kf = *(const bf16x8*)&k[(size_t)(row0 + r) * D_ + h * DK_ + quad * 8];
    f16x4 va = *(const f16x4*)vta;
    f16x4 vb = *(const f16x4*)vtb;
    for (int kt = 0; kt < nk; ++kt) {
        bf16x8 kf_n = kf;
        f16x4 va_n = va, vb_n = vb;
        if (kt + 1 < nk) {
            kf_n = *(const bf16x8*)&k[(size_t)(row0 + (kt + 1) * 16 + r) * D_ + h * DK_ + quad * 8];
            va_n = *(const f16x4*)(vta + (kt + 1) * 16);
            vb_n = *(const f16x4*)(vtb + (kt + 1) * 16);
        }
        f32x4 zero = {};
        f32x4 s = __builtin_amdgcn_mfma_f32_16x16x32_bf16(kf, qf, zero, 0, 0, 0);
#pragma unroll
        for (int i2 = 0; i2 < 4; ++i2) s[i2] *= 0.17677669529663687f;
        if (kt == qt) {
#pragma unroll
            for (int i2 = 0; i2 < 4; ++i2)
                if (quad * 4 + i2 > r) s[i2] = -1e30f;
        }
        float tmax = fmaxf(fmaxf(s[0], s[1]), fmaxf(s[2], s[3]));
        tmax = fmaxf(tmax, __shfl_xor(tmax, 16, 64));
        tmax = fmaxf(tmax, __shfl_xor(tmax, 32, 64));
        float mn = fmaxf(mA, tmax);
        float alpha = __expf(mA - mn);
        mA = mn;
        float p0 = __expf(s[0] - mn), p1 = __expf(s[1] - mn);
        float p2 = __expf(s[2] - mn), p3 = __expf(s[3] - mn);
        float ts = (p0 + p1) + (p2 + p3);
        ts += __shfl_xor(ts, 16, 64);
        ts += __shfl_xor(ts, 32, 64);
        den = den * alpha + ts;
        f16x4 pf;
        pf[0] = (_Float16)p0; pf[1] = (_Float16)p1; pf[2] = (_Float16)p2; pf[3] = (_Float16)p3;
        float al[4];
#pragma unroll
        for (int i2 = 0; i2 < 4; ++i2) al[i2] = __shfl(alpha, quad * 4 + i2, 64);
#pragma unroll
        for (int i2 = 0; i2 < 4; ++i2) { O0[i2] *= al[i2]; O1[i2] *= al[i2]; }
        O0 = __builtin_amdgcn_mfma_f32_16x16x16f16(pf, va, O0, 0, 0, 0);
        O1 = __builtin_amdgcn_mfma_f32_16x16x16f16(pf, vb, O1, 0, 0, 0);
        kf = kf_n; va = va_n; vb = vb_n;
    }
#pragma unroll
    for (int i2 = 0; i2 < 4; ++i2) {
        float inv = 1.0f / __shfl(den, quad * 4 + i2, 64);
        int rowz = row0 + qt * 16 + quad * 4 + i2;
        z[(size_t)rowz * D_ + h * DK_ + r] = f2b(O0[i2] * inv);
        z[(size_t)rowz * D_ + h * DK_ + 16 + r] = f2b(O1[i2] * inv);
    }
}

// in-place log_softmax over V=2048, one block per row
__global__ void lsm_kernel(float* __restrict__ logits) {
    __shared__ float rm[4], rs[4];
    int row = blockIdx.x, t = threadIdx.x;
    float* p = logits + (size_t)row * V_;
    float vals[8];
    float mx = -INFINITY;
#pragma unroll
    for (int i = 0; i < 8; ++i) {
        vals[i] = p[t + i * 256];
        mx = fmaxf(mx, vals[i]);
    }
#pragma unroll
    for (int off = 32; off; off >>= 1) mx = fmaxf(mx, __shfl_xor(mx, off, 64));
    int w = t >> 6;
    if ((t & 63) == 0) rm[w] = mx;
    __syncthreads();
    mx = fmaxf(fmaxf(rm[0], rm[1]), fmaxf(rm[2], rm[3]));
    float s = 0.f;
#pragma unroll
    for (int i = 0; i < 8; ++i) s += __expf(vals[i] - mx);
#pragma unroll
    for (int off = 32; off; off >>= 1) s += __shfl_xor(s, off, 64);
    if ((t & 63) == 0) rs[w] = s;
    __syncthreads();
    s = rs[0] + rs[1] + rs[2] + rs[3];
    float lse = mx + logf(s);
#pragma unroll
    for (int i = 0; i < 8; ++i) p[t + i * 256] = vals[i] - lse;
}

extern "C" void kernel_launch(void* const* d_in, const int* in_sizes, int n_in,
                              void* d_out, int out_size, void* d_ws, size_t ws_size,
                              hipStream_t stream) {
    const int* tokens = (const int*)d_in[0];
    const int* positions = (const int*)d_in[1];
    // d_in[2]=src, d_in[3]=dst: deterministic causal structure — unused
    const float* vtab = (const float*)d_in[4];
    const float* ctab = (const float*)d_in[5];
    const float* ptab = (const float*)d_in[6];
    const float* ln1_g = (const float*)d_in[7];
    const float* ln1_b = (const float*)d_in[8];
    const float* Wq = (const float*)d_in[9];
    const float* Wk = (const float*)d_in[10];
    const float* Wv = (const float*)d_in[11];
    const float* Wo = (const float*)d_in[12];
    const float* ln2_g = (const float*)d_in[13];
    const float* ln2_b = (const float*)d_in[14];
    const float* W1 = (const float*)d_in[15];
    const float* b1 = (const float*)d_in[16];
    const float* W2 = (const float*)d_in[17];
    const float* b2 = (const float*)d_in[18];
    const float* lnf_g = (const float*)d_in[19];
    const float* lnf_b = (const float*)d_in[20];
    const float* Wgen = (const float*)d_in[21];
    const float* bgen = (const float*)d_in[22];

    char* p = (char*)d_ws;
    float* x = (float*)p;      p += (size_t)N_ * D_ * 4;
    short* qb = (short*)p;     p += (size_t)N_ * D_ * 2;   // bf16 [N,D]
    short* kb = (short*)p;     p += (size_t)N_ * D_ * 2;   // bf16 [N,D]
    _Float16* vt = (_Float16*)p; p += (size_t)D_ * N_ * 2; // f16  [D,N] transposed
    short* zbb = (short*)p;    p += (size_t)N_ * D_ * 2;
    short* hbb = (short*)p;    p += (size_t)N_ * FF_ * 2;
    short* wqT = (short*)p;    p += (size_t)NL_ * D_ * D_ * 2;
    short* wkT = (short*)p;    p += (size_t)NL_ * D_ * D_ * 2;
    short* wvT = (short*)p;    p += (size_t)NL_ * D_ * D_ * 2;
    short* woT = (short*)p;    p += (size_t)NL_ * D_ * D_ * 2;
    short* w1T = (short*)p;    p += (size_t)NL_ * D_ * FF_ * 2;
    short* w2T = (short*)p;    p += (size_t)NL_ * FF_ * D_ * 2;
    short* wgT = (short*)p;    p += (size_t)D_ * V_ * 2;
    float* out = (float*)d_out;

    dim3 tb(32, 8);
    transpose_w4<<<dim3(8, 8, 16), tb, 0, stream>>>(Wq, Wk, Wv, Wo, wqT, wkT, wvT, woT);
    transpose_w<<<dim3(32, 8, NL_), tb, 0, stream>>>(W1, w1T, D_, FF_);
    transpose_w<<<dim3(8, 32, NL_), tb, 0, stream>>>(W2, w2T, FF_, D_);
    transpose_w<<<dim3(64, 8, 1), tb, 0, stream>>>(Wgen, wgT, D_, V_);

    embed_kernel<<<N_, 256, 0, stream>>>(tokens, positions, vtab, ctab, ptab, x);
    dim3 gQKV(N_ / 64, D_ / 64, 3);   // 384 blocks
    dim3 gWo(N_ / 64, D_ / 64, 2);    // 256 blocks, split-K 2 (Kp=128)
    dim3 gW1(N_ / 64, FF_ / 64);      // 512 blocks
    dim3 gW2(N_ / 64, D_ / 64, 4);    // 512 blocks, split-K 4 (Kp=256)
    dim3 gGen(N_ / 64, V_ / 64);      // 1024 blocks
    for (int i = 0; i < NL_; ++i) {
        gemm_qkv<<<gQKV, 256, 0, stream>>>(x, wqT + (size_t)i * D_ * D_, wkT + (size_t)i * D_ * D_,
                                           wvT + (size_t)i * D_ * D_, ln1_g + i * D_, ln1_b + i * D_,
                                           qb, kb, vt, N_, D_, D_);
        attn_kernel<<<B_ * H_ * 16, 64, 0, stream>>>(qb, kb, vt, zbb);
        gemm_accum<2, false><<<gWo, 256, 0, stream>>>(zbb, woT + (size_t)i * D_ * D_, nullptr, x, N_, D_, D_);
        gemm_lnrelu<<<gW1, 256, 0, stream>>>(x, w1T + (size_t)i * D_ * FF_, ln2_g + i * D_, ln2_b + i * D_,
                                             b1 + (size_t)i * FF_, hbb, N_, D_, FF_);
        gemm_accum<4, true><<<gW2, 256, 0, stream>>>(hbb, w2T + (size_t)i * FF_ * D_, b2 + (size_t)i * D_,
                                                     x, N_, FF_, D_);
    }
    gemm_lnbias<<<gGen, 256, 0, stream>>>(x, wgT, lnf_g, lnf_b, bgen, out, N_, D_, V_);
    lsm_kernel<<<N_, 256, 0, stream>>>(out);
}

// Round 9
// 338.278 us; speedup vs baseline: 1.1230x; 1.1230x over previous
//
#include <hip/hip_runtime.h>
#include <hip/hip_bf16.h>
#include <math.h>

constexpr int B_ = 8, L_ = 256, D_ = 256, H_ = 8, DK_ = 32, NL_ = 4, V_ = 2048, FF_ = 1024;
constexpr int N_ = B_ * L_;
constexpr float EPS_ = 1e-5f;

typedef short bf16x8 __attribute__((ext_vector_type(8)));
typedef float f32x4 __attribute__((ext_vector_type(4)));
typedef _Float16 f16x4 __attribute__((ext_vector_type(4)));

__device__ __forceinline__ short f2b(float f) {
    union { __hip_bfloat16 h; short s; } u;
    u.h = __float2bfloat16(f);
    return u.s;
}

// async 16B/lane global->LDS (global_load_lds_dwordx4). LDS dest = wave-uniform
// base + lane*16. Proven correct in R6.
__device__ __forceinline__ void load16_lds(const void* g, void* l) {
    auto gp = reinterpret_cast<const __attribute__((address_space(1))) unsigned int*>(
        reinterpret_cast<unsigned long long>(g));
    auto lp = reinterpret_cast<__attribute__((address_space(3))) unsigned int*>(
        (unsigned int)reinterpret_cast<unsigned long long>(l));
    __builtin_amdgcn_global_load_lds(gp, lp, 16, 0, 0);
}

// x[n,d] = value_tab[tok]*sqrt(D) + coord_tab[p%3] + pos_tab[p/3]  (fp32 residual stream)
__global__ void embed_kernel(const int* __restrict__ tokens, const int* __restrict__ positions,
                             const float* __restrict__ vtab, const float* __restrict__ ctab,
                             const float* __restrict__ ptab, float* __restrict__ x) {
    int n = blockIdx.x, d = threadIdx.x;
    int tok = tokens[n], p = positions[n];
    x[n * D_ + d] = vtab[tok * D_ + d] * 16.0f + ctab[(p % 3) * D_ + d] + ptab[(p / 3) * D_ + d];
}

// LayerNorm, writes bf16 (all consumers are MFMA GEMMs)
__global__ void ln_kernel(const float* __restrict__ x, const float* __restrict__ g,
                          const float* __restrict__ b, short* __restrict__ out) {
    __shared__ float r1[4], r2[4], mv[2];
    int n = blockIdx.x, t = threadIdx.x;
    float v = x[n * D_ + t];
    float s1 = v, s2 = v * v;
#pragma unroll
    for (int off = 32; off; off >>= 1) {
        s1 += __shfl_down(s1, off, 64);
        s2 += __shfl_down(s2, off, 64);
    }
    int w = t >> 6;
    if ((t & 63) == 0) { r1[w] = s1; r2[w] = s2; }
    __syncthreads();
    if (t == 0) {
        float a = r1[0] + r1[1] + r1[2] + r1[3];
        float c = r2[0] + r2[1] + r2[2] + r2[3];
        float mean = a * (1.0f / D_);
        float var = c * (1.0f / D_) - mean * mean;
        mv[0] = mean;
        mv[1] = rsqrtf(var + EPS_);
    }
    __syncthreads();
    out[n * D_ + t] = f2b((v - mv[0]) * mv[1] * g[t] + b[t]);
}

// fp32 [K,N] -> bf16 [N,K] tiled transpose; batch via blockIdx.z
__global__ void transpose_w(const float* __restrict__ src, short* __restrict__ dst, int K, int Nn) {
    __shared__ float tile[32][33];
    int n0 = blockIdx.x * 32, k0 = blockIdx.y * 32;
    size_t base = (size_t)blockIdx.z * K * Nn;
    src += base;
    dst += base;
    int tx = threadIdx.x, ty = threadIdx.y;  // 32 x 8
#pragma unroll
    for (int i = 0; i < 32; i += 8)
        tile[ty + i][tx] = src[(size_t)(k0 + ty + i) * Nn + n0 + tx];
    __syncthreads();
#pragma unroll
    for (int i = 0; i < 32; i += 8)
        dst[(size_t)(n0 + ty + i) * K + k0 + tx] = f2b(tile[tx][ty + i]);
}

// all four DxD weight families in one launch: z = layer*4 + matrix
__global__ void transpose_w4(const float* __restrict__ Wq, const float* __restrict__ Wk,
                             const float* __restrict__ Wv, const float* __restrict__ Wo,
                             short* __restrict__ wqT, short* __restrict__ wkT,
                             short* __restrict__ wvT, short* __restrict__ woT) {
    __shared__ float tile[32][33];
    int z = blockIdx.z, m = z & 3, layer = z >> 2;
    const float* src = (m == 0) ? Wq : (m == 1) ? Wk : (m == 2) ? Wv : Wo;
    short* dst = (m == 0) ? wqT : (m == 1) ? wkT : (m == 2) ? wvT : woT;
    src += (size_t)layer * D_ * D_;
    dst += (size_t)layer * D_ * D_;
    int n0 = blockIdx.x * 32, k0 = blockIdx.y * 32;
    int tx = threadIdx.x, ty = threadIdx.y;
#pragma unroll
    for (int i = 0; i < 32; i += 8)
        tile[ty + i][tx] = src[(size_t)(k0 + ty + i) * D_ + n0 + tx];
    __syncthreads();
#pragma unroll
    for (int i = 0; i < 32; i += 8)
        dst[(size_t)(n0 + ty + i) * D_ + k0 + tx] = f2b(tile[tx][ty + i]);
}

// 64x64 tile bf16 MFMA GEMM body (BK=32, reg-prefetch, stride-40 LDS = 2-way-only
// bank aliasing). LDS hoisted to caller (single allocation per kernel).
// EPI: 2 = atomicAdd fp32 (+bias from kz==0); 4 = store bf16; 5 = store f16
template <int EPI, bool HAS_BIAS>
__device__ __forceinline__ void gemm_body(short (*As)[40], short (*Bs)[40],
                                          const short* __restrict__ A, const short* __restrict__ Bt,
                                          const float* __restrict__ bias, float* __restrict__ Cf,
                                          short* __restrict__ Cb, int K, int Nout,
                                          int kbeg, int kend, int kz) {
    int t = threadIdx.x;
    int m0 = blockIdx.x * 64, n0 = blockIdx.y * 64;
    int lane = t & 63, w = t >> 6;
    int mo = (w & 1) * 32, no = (w >> 1) * 32;
    int quad = lane >> 4, r = lane & 15;
    f32x4 acc00 = {}, acc01 = {}, acc10 = {}, acc11 = {};
    int sr = t >> 2, sc = (t & 3) * 8;
    const short* Ap = &A[(size_t)(m0 + sr) * K + sc];
    const short* Bg = &Bt[(size_t)(n0 + sr) * K + sc];
    int4 aR = *(const int4*)(Ap + kbeg);
    int4 bR = *(const int4*)(Bg + kbeg);
    for (int k0 = kbeg; k0 < kend; k0 += 32) {
        __syncthreads();
        *(int4*)&As[sr][sc] = aR;
        *(int4*)&Bs[sr][sc] = bR;
        __syncthreads();
        if (k0 + 32 < kend) {
            aR = *(const int4*)(Ap + k0 + 32);
            bR = *(const int4*)(Bg + k0 + 32);
        }
        bf16x8 a0 = *(const bf16x8*)&As[mo + r][quad * 8];
        bf16x8 a1 = *(const bf16x8*)&As[mo + 16 + r][quad * 8];
        bf16x8 b0 = *(const bf16x8*)&Bs[no + r][quad * 8];
        bf16x8 b1 = *(const bf16x8*)&Bs[no + 16 + r][quad * 8];
        acc00 = __builtin_amdgcn_mfma_f32_16x16x32_bf16(a0, b0, acc00, 0, 0, 0);
        acc01 = __builtin_amdgcn_mfma_f32_16x16x32_bf16(a0, b1, acc01, 0, 0, 0);
        acc10 = __builtin_amdgcn_mfma_f32_16x16x32_bf16(a1, b0, acc10, 0, 0, 0);
        acc11 = __builtin_amdgcn_mfma_f32_16x16x32_bf16(a1, b1, acc11, 0, 0, 0);
    }
#pragma unroll
    for (int i = 0; i < 2; ++i) {
#pragma unroll
        for (int j = 0; j < 2; ++j) {
            f32x4 acc = (i == 0) ? (j == 0 ? acc00 : acc01) : (j == 0 ? acc10 : acc11);
            int col = n0 + no + j * 16 + r;
            float bval = HAS_BIAS ? bias[col] : 0.f;
#pragma unroll
            for (int p = 0; p < 4; ++p) {
                int row = m0 + mo + i * 16 + quad * 4 + p;
                float v = acc[p];
                if (EPI == 2) {
                    float add = v + ((HAS_BIAS && kz == 0) ? bval : 0.f);
                    atomicAdd(&Cf[(size_t)row * Nout + col], add);
                } else if (EPI == 4) {
                    Cb[(size_t)row * Nout + col] = f2b(v);
                } else {
                    ((_Float16*)Cb)[(size_t)row * Nout + col] = (_Float16)v;
                }
            }
        }
    }
}

// fused Q/K/V projection: q,k -> bf16; v -> f16 (PV mfma uses f16). LDS hoisted.
__global__ __launch_bounds__(256) void gemm_qkv(const short* __restrict__ A, const short* __restrict__ wq,
                                                const short* __restrict__ wk, const short* __restrict__ wv,
                                                short* __restrict__ q, short* __restrict__ k,
                                                short* __restrict__ v, int K, int Nout) {
    __shared__ short As[64][40];
    __shared__ short Bs[64][40];
    if (blockIdx.z == 0)
        gemm_body<4, false>(As, Bs, A, wq, nullptr, nullptr, q, K, Nout, 0, K, 0);
    else if (blockIdx.z == 1)
        gemm_body<4, false>(As, Bs, A, wk, nullptr, nullptr, k, K, Nout, 0, K, 0);
    else
        gemm_body<5, false>(As, Bs, A, wv, nullptr, nullptr, v, K, Nout, 0, K, 0);
}

// split-K accumulate into fp32 residual stream (bias applied by the kz==0 split only)
template <int SPLITK, bool HAS_BIAS>
__global__ __launch_bounds__(256) void gemm_accum(const short* __restrict__ A, const short* __restrict__ Bt,
                                                  const float* __restrict__ bias, float* __restrict__ C,
                                                  int K, int Nout) {
    __shared__ short As[64][40];
    __shared__ short Bs[64][40];
    int Kp = K / SPLITK;
    int kz = blockIdx.z;
    gemm_body<2, HAS_BIAS>(As, Bs, A, Bt, bias, C, nullptr, K, Nout, kz * Kp, kz * Kp + Kp, kz);
}

// 128x128-tile bf16 MFMA GEMM (m97 structure): BK=64, global_load_lds width-16
// staging, 4 waves each computing 64x64 via 4x4 16x16x32 fragments.
// EPI: 1 = bias+relu -> bf16; 3 = bias -> fp32
template <int EPI>
__global__ __launch_bounds__(256) void gemm128(const short* __restrict__ A, const short* __restrict__ Bt,
                                               const float* __restrict__ bias, float* __restrict__ Cf,
                                               short* __restrict__ Cb, int K, int Nout) {
    __shared__ short As[128][64];
    __shared__ short Bs[128][64];
    int t = threadIdx.x;
    int m0 = blockIdx.x * 128, n0 = blockIdx.y * 128;
    int lane = t & 63, w = t >> 6;
    int wr = (w & 1) * 64, wc = (w >> 1) * 64;
    int quad = lane >> 4, r = lane & 15;
    f32x4 acc[4][4] = {};
    // staging: wave w covers 32 rows of A and 32 rows of Bt per chunk, 4 ops x 8 rows each
    int srow = lane >> 3, scol = (lane & 7) * 8;
    const short* Ag = &A[(size_t)(m0 + 32 * w + srow) * K + scol];
    const short* Bg = &Bt[(size_t)(n0 + 32 * w + srow) * K + scol];
    for (int k0 = 0; k0 < K; k0 += 64) {
        __syncthreads();
#pragma unroll
        for (int op = 0; op < 4; ++op) {
            load16_lds(Ag + (size_t)(8 * op) * K + k0, &As[32 * w + 8 * op][0]);
            load16_lds(Bg + (size_t)(8 * op) * K + k0, &Bs[32 * w + 8 * op][0]);
        }
        __syncthreads();
#pragma unroll
        for (int kk = 0; kk < 64; kk += 32) {
            bf16x8 af[4], bf[4];
#pragma unroll
            for (int i = 0; i < 4; ++i) af[i] = *(const bf16x8*)&As[wr + i * 16 + r][kk + quad * 8];
#pragma unroll
            for (int j = 0; j < 4; ++j) bf[j] = *(const bf16x8*)&Bs[wc + j * 16 + r][kk + quad * 8];
#pragma unroll
            for (int i = 0; i < 4; ++i)
#pragma unroll
                for (int j = 0; j < 4; ++j)
                    acc[i][j] = __builtin_amdgcn_mfma_f32_16x16x32_bf16(af[i], bf[j], acc[i][j], 0, 0, 0);
        }
    }
#pragma unroll
    for (int i = 0; i < 4; ++i) {
#pragma unroll
        for (int j = 0; j < 4; ++j) {
            int col = n0 + wc + j * 16 + r;
            float bval = bias[col];
#pragma unroll
            for (int p = 0; p < 4; ++p) {
                int row = m0 + wr + i * 16 + quad * 4 + p;
                float v = acc[i][j][p] + bval;
                if (EPI == 1) {
                    Cb[(size_t)row * Nout + col] = f2b(fmaxf(v, 0.f));
                } else {
                    Cf[(size_t)row * Nout + col] = v;
                }
            }
        }
    }
}

// MFMA flash attention. One wave per (b,h,q-tile of 16 queries). R4-proven.
__global__ __launch_bounds__(64) void attn_kernel(const short* __restrict__ q,
                                                  const short* __restrict__ k,
                                                  const _Float16* __restrict__ v,
                                                  short* __restrict__ z) {
    int blk = blockIdx.x;
    int bh = blk & 63;
    int qt = 15 - (blk >> 6);  // heavy q-tiles dispatched first
    int b = bh >> 3, h = bh & 7;
    int lane = threadIdx.x;
    int r = lane & 15, quad = lane >> 4;
    int row0 = b * L_;

    bf16x8 qf = *(const bf16x8*)&q[(size_t)(row0 + qt * 16 + r) * D_ + h * DK_ + quad * 8];
    f32x4 O0 = {}, O1 = {};
    float mA = -1e30f, den = 0.f;
    int nk = qt + 1;

    bf16x8 kf = *(const bf16x8*)&k[(size_t)(row0 + r) * D_ + h * DK_ + quad * 8];
    f16x4 va, vb;
    {
        const _Float16* vp = v + (size_t)(row0 + quad * 4) * D_ + h * DK_;
#pragma unroll
        for (int i = 0; i < 4; ++i) {
            va[i] = vp[(size_t)i * D_ + r];
            vb[i] = vp[(size_t)i * D_ + 16 + r];
        }
    }
    for (int kt = 0; kt < nk; ++kt) {
        bf16x8 kf_n = kf;
        f16x4 va_n = va, vb_n = vb;
        if (kt + 1 < nk) {
            kf_n = *(const bf16x8*)&k[(size_t)(row0 + (kt + 1) * 16 + r) * D_ + h * DK_ + quad * 8];
            const _Float16* vp = v + (size_t)(row0 + (kt + 1) * 16 + quad * 4) * D_ + h * DK_;
#pragma unroll
            for (int i = 0; i < 4; ++i) {
                va_n[i] = vp[(size_t)i * D_ + r];
                vb_n[i] = vp[(size_t)i * D_ + 16 + r];
            }
        }
        f32x4 zero = {};
        f32x4 s = __builtin_amdgcn_mfma_f32_16x16x32_bf16(kf, qf, zero, 0, 0, 0);
#pragma unroll
        for (int i2 = 0; i2 < 4; ++i2) s[i2] *= 0.17677669529663687f;
        if (kt == qt) {
#pragma unroll
            for (int i2 = 0; i2 < 4; ++i2)
                if (quad * 4 + i2 > r) s[i2] = -1e30f;
        }
        float tmax = fmaxf(fmaxf(s[0], s[1]), fmaxf(s[2], s[3]));
        tmax = fmaxf(tmax, __shfl_xor(tmax, 16, 64));
        tmax = fmaxf(tmax, __shfl_xor(tmax, 32, 64));
        float mn = fmaxf(mA, tmax);
        float alpha = __expf(mA - mn);
        mA = mn;
        float p0 = __expf(s[0] - mn), p1 = __expf(s[1] - mn);
        float p2 = __expf(s[2] - mn), p3 = __expf(s[3] - mn);
        float ts = (p0 + p1) + (p2 + p3);
        ts += __shfl_xor(ts, 16, 64);
        ts += __shfl_xor(ts, 32, 64);
        den = den * alpha + ts;
        f16x4 pf;
        pf[0] = (_Float16)p0; pf[1] = (_Float16)p1; pf[2] = (_Float16)p2; pf[3] = (_Float16)p3;
        float al[4];
#pragma unroll
        for (int i2 = 0; i2 < 4; ++i2) al[i2] = __shfl(alpha, quad * 4 + i2, 64);
#pragma unroll
        for (int i2 = 0; i2 < 4; ++i2) { O0[i2] *= al[i2]; O1[i2] *= al[i2]; }
        O0 = __builtin_amdgcn_mfma_f32_16x16x16f16(pf, va, O0, 0, 0, 0);
        O1 = __builtin_amdgcn_mfma_f32_16x16x16f16(pf, vb, O1, 0, 0, 0);
        kf = kf_n; va = va_n; vb = vb_n;
    }
#pragma unroll
    for (int i2 = 0; i2 < 4; ++i2) {
        float inv = 1.0f / __shfl(den, quad * 4 + i2, 64);
        int rowz = row0 + qt * 16 + quad * 4 + i2;
        z[(size_t)rowz * D_ + h * DK_ + r] = f2b(O0[i2] * inv);
        z[(size_t)rowz * D_ + h * DK_ + 16 + r] = f2b(O1[i2] * inv);
    }
}

// in-place log_softmax over V=2048, one block per row
__global__ void lsm_kernel(float* __restrict__ logits) {
    __shared__ float rm[4], rs[4];
    int row = blockIdx.x, t = threadIdx.x;
    float* p = logits + (size_t)row * V_;
    float vals[8];
    float mx = -INFINITY;
#pragma unroll
    for (int i = 0; i < 8; ++i) {
        vals[i] = p[t + i * 256];
        mx = fmaxf(mx, vals[i]);
    }
#pragma unroll
    for (int off = 32; off; off >>= 1) mx = fmaxf(mx, __shfl_xor(mx, off, 64));
    int w = t >> 6;
    if ((t & 63) == 0) rm[w] = mx;
    __syncthreads();
    mx = fmaxf(fmaxf(rm[0], rm[1]), fmaxf(rm[2], rm[3]));
    float s = 0.f;
#pragma unroll
    for (int i = 0; i < 8; ++i) s += __expf(vals[i] - mx);
#pragma unroll
    for (int off = 32; off; off >>= 1) s += __shfl_xor(s, off, 64);
    if ((t & 63) == 0) rs[w] = s;
    __syncthreads();
    s = rs[0] + rs[1] + rs[2] + rs[3];
    float lse = mx + logf(s);
#pragma unroll
    for (int i = 0; i < 8; ++i) p[t + i * 256] = vals[i] - lse;
}

extern "C" void kernel_launch(void* const* d_in, const int* in_sizes, int n_in,
                              void* d_out, int out_size, void* d_ws, size_t ws_size,
                              hipStream_t stream) {
    const int* tokens = (const int*)d_in[0];
    const int* positions = (const int*)d_in[1];
    // d_in[2]=src, d_in[3]=dst: deterministic causal structure — unused
    const float* vtab = (const float*)d_in[4];
    const float* ctab = (const float*)d_in[5];
    const float* ptab = (const float*)d_in[6];
    const float* ln1_g = (const float*)d_in[7];
    const float* ln1_b = (const float*)d_in[8];
    const float* Wq = (const float*)d_in[9];
    const float* Wk = (const float*)d_in[10];
    const float* Wv = (const float*)d_in[11];
    const float* Wo = (const float*)d_in[12];
    const float* ln2_g = (const float*)d_in[13];
    const float* ln2_b = (const float*)d_in[14];
    const float* W1 = (const float*)d_in[15];
    const float* b1 = (const float*)d_in[16];
    const float* W2 = (const float*)d_in[17];
    const float* b2 = (const float*)d_in[18];
    const float* lnf_g = (const float*)d_in[19];
    const float* lnf_b = (const float*)d_in[20];
    const float* Wgen = (const float*)d_in[21];
    const float* bgen = (const float*)d_in[22];

    char* p = (char*)d_ws;
    float* x = (float*)p;      p += (size_t)N_ * D_ * 4;
    short* qb = (short*)p;     p += (size_t)N_ * D_ * 2;   // bf16 [N,D]
    short* kb = (short*)p;     p += (size_t)N_ * D_ * 2;   // bf16 [N,D]
    short* vbh = (short*)p;    p += (size_t)N_ * D_ * 2;   // f16  [N,D]
    short* xnb = (short*)p;    p += (size_t)N_ * D_ * 2;
    short* zbb = (short*)p;    p += (size_t)N_ * D_ * 2;
    short* hbb = (short*)p;    p += (size_t)N_ * FF_ * 2;
    short* wqT = (short*)p;    p += (size_t)NL_ * D_ * D_ * 2;
    short* wkT = (short*)p;    p += (size_t)NL_ * D_ * D_ * 2;
    short* wvT = (short*)p;    p += (size_t)NL_ * D_ * D_ * 2;
    short* woT = (short*)p;    p += (size_t)NL_ * D_ * D_ * 2;
    short* w1T = (short*)p;    p += (size_t)NL_ * D_ * FF_ * 2;
    short* w2T = (short*)p;    p += (size_t)NL_ * FF_ * D_ * 2;
    short* wgT = (short*)p;    p += (size_t)D_ * V_ * 2;
    float* out = (float*)d_out;

    dim3 tb(32, 8);
    transpose_w4<<<dim3(8, 8, 16), tb, 0, stream>>>(Wq, Wk, Wv, Wo, wqT, wkT, wvT, woT);
    transpose_w<<<dim3(32, 8, NL_), tb, 0, stream>>>(W1, w1T, D_, FF_);
    transpose_w<<<dim3(8, 32, NL_), tb, 0, stream>>>(W2, w2T, FF_, D_);
    transpose_w<<<dim3(64, 8, 1), tb, 0, stream>>>(Wgen, wgT, D_, V_);

    embed_kernel<<<N_, 256, 0, stream>>>(tokens, positions, vtab, ctab, ptab, x);
    dim3 gQKV(N_ / 64, D_ / 64, 3);     // 384 blocks
    dim3 gWo(N_ / 64, D_ / 64, 2);      // 256 blocks, split-K 2
    dim3 gW1(N_ / 128, FF_ / 128);      // 128 blocks, 128-tile
    dim3 gW2(N_ / 64, D_ / 64, 4);      // 512 blocks, split-K 4
    dim3 gGen(N_ / 128, V_ / 128);      // 256 blocks, 128-tile
    for (int i = 0; i < NL_; ++i) {
        ln_kernel<<<N_, 256, 0, stream>>>(x, ln1_g + i * D_, ln1_b + i * D_, xnb);
        gemm_qkv<<<gQKV, 256, 0, stream>>>(xnb, wqT + (size_t)i * D_ * D_, wkT + (size_t)i * D_ * D_,
                                           wvT + (size_t)i * D_ * D_, qb, kb, vbh, D_, D_);
        attn_kernel<<<B_ * H_ * 16, 64, 0, stream>>>(qb, kb, (const _Float16*)vbh, zbb);
        gemm_accum<2, false><<<gWo, 256, 0, stream>>>(zbb, woT + (size_t)i * D_ * D_, nullptr, x, D_, D_);
        ln_kernel<<<N_, 256, 0, stream>>>(x, ln2_g + i * D_, ln2_b + i * D_, xnb);
        gemm128<1><<<gW1, 256, 0, stream>>>(xnb, w1T + (size_t)i * D_ * FF_, b1 + (size_t)i * FF_,
                                            nullptr, hbb, D_, FF_);
        gemm_accum<4, true><<<gW2, 256, 0, stream>>>(hbb, w2T + (size_t)i * FF_ * D_, b2 + (size_t)i * D_,
                                                     x, FF_, D_);
    }
    ln_kernel<<<N_, 256, 0, stream>>>(x, lnf_g, lnf_b, xnb);
    gemm128<3><<<gGen, 256, 0, stream>>>(xnb, wgT, bgen, out, nullptr, D_, V_);
    lsm_kernel<<<N_, 256, 0, stream>>>(out);
}